// Round 3
// baseline (1005.605 us; speedup 1.0000x reference)
//
#include <hip/hip_runtime.h>

// Problem constants (fixed by the reference)
constexpr int Nn = 16384;   // nodes at current level
constexpr int Mm = 8192;    // K of big GEMM
constexpr int Ee = 524288;  // edges
constexpr int Dd = 128;     // feature dim

typedef __attribute__((ext_vector_type(8))) short short8v;
typedef __attribute__((ext_vector_type(4))) short short4v;
typedef __attribute__((ext_vector_type(4))) float float4v;

// f32 -> bf16 round-to-nearest-even (inputs finite; no NaN handling needed)
static __device__ __forceinline__ short f2bf(float f) {
    unsigned u = __builtin_bit_cast(unsigned, f);
    u += 0x7fffu + ((u >> 16) & 1u);
    return (short)(u >> 16);
}

// ---------------------------------------------------------------------------
// k_bt_zero: blocks 0..1023 transpose+convert next_h [8192][128] f32 ->
// Bt [128][8192] bf16; blocks 1024.. zero the 3*Nn int counters.
// ---------------------------------------------------------------------------
__global__ void k_bt_zero(const float* __restrict__ B, short* __restrict__ Bt,
                          int* __restrict__ zp) {
    int b = blockIdx.x;
    if (b >= 1024) {
        int i = (b - 1024) * 256 + threadIdx.x;
        if (i < 3 * Nn) zp[i] = 0;
        return;
    }
    __shared__ short T[32][40];     // [n_local][k_local], padded
    int kt = b & 255;               // k tile (32 wide)
    int nt = b >> 8;                // n tile (32 wide), 0..3
    int t = threadIdx.x;
    int r = t >> 3;                 // k_local 0..31
    int c4 = (t & 7) * 4;           // n_local 0,4..28
    float4 v = *(const float4*)(B + (size_t)(kt * 32 + r) * 128 + nt * 32 + c4);
    T[c4 + 0][r] = f2bf(v.x);
    T[c4 + 1][r] = f2bf(v.y);
    T[c4 + 2][r] = f2bf(v.z);
    T[c4 + 3][r] = f2bf(v.w);
    __syncthreads();
    int nl = t >> 3, ks = (t & 7) * 4;
    *(short4v*)(Bt + (size_t)(nt * 32 + nl) * 8192 + kt * 32 + ks) =
        *(const short4v*)(&T[nl][ks]);
}

// ---------------------------------------------------------------------------
// Degree count (int atomics; 32-way avg contention, cheap)
// ---------------------------------------------------------------------------
__global__ void k_deg_count(const int* __restrict__ src, const int* __restrict__ dst,
                            int* __restrict__ cnt_out, int* __restrict__ cnt_in) {
    int e = blockIdx.x * 256 + threadIdx.x;
    if (e < Ee) {
        atomicAdd(&cnt_out[src[e]], 1);
        atomicAdd(&cnt_in[dst[e]], 1);
    }
}

// Exclusive prefix sum of cnt_in -> row_start[16385]; also rs_out/rs_in.
__global__ void k_scan(const int* __restrict__ cnt_in, const int* __restrict__ cnt_out,
                       int* __restrict__ row_start,
                       float* __restrict__ rs_in, float* __restrict__ rs_out) {
    __shared__ int s[1024];
    int t = threadIdx.x;
    int base = t * 16;
    int local[16];
    int sum = 0;
#pragma unroll
    for (int i = 0; i < 16; i++) {
        int ci = cnt_in[base + i];
        local[i] = ci;
        sum += ci;
        rs_in[base + i]  = rsqrtf((float)(ci + 1));                  // +1 self-loop
        rs_out[base + i] = rsqrtf((float)(cnt_out[base + i] + 1));
    }
    s[t] = sum;
    __syncthreads();
    for (int off = 1; off < 1024; off <<= 1) {
        int v = (t >= off) ? s[t - off] : 0;
        __syncthreads();
        s[t] += v;
        __syncthreads();
    }
    int run = s[t] - sum;   // exclusive offset for this thread's chunk
#pragma unroll
    for (int i = 0; i < 16; i++) { row_start[base + i] = run; run += local[i]; }
    if (t == 1023) row_start[16384] = s[1023];
}

__global__ void k_fill(const int* __restrict__ src, const int* __restrict__ dst,
                       const int* __restrict__ row_start, int* __restrict__ cursor,
                       int* __restrict__ ebuf) {
    int e = blockIdx.x * 256 + threadIdx.x;
    if (e < Ee) {
        int d = dst[e];
        int pos = atomicAdd(&cursor[d], 1);
        ebuf[row_start[d] + pos] = src[e];
    }
}

// ---------------------------------------------------------------------------
// Big GEMM via MFMA: fused[16384][128] = curr_inc[16384][8192] @ next_h
// A converted f32->bf16 in-kernel (A read from HBM exactly once).
// Tile: 32 rows x 128 cols, BK=64, 256 threads (4 waves, wave = 32-col slice).
// Verified gfx950 layouts: A-frag A[m=lane&15][k=(lane>>4)*8+j];
//                          C/D col=lane&15, row=(lane>>4)*4+reg.
// ---------------------------------------------------------------------------
__launch_bounds__(256, 2)
__global__ void k_mfma_gemm(const float* __restrict__ A, const short* __restrict__ Bt,
                            float* __restrict__ C) {
    __shared__ short As[32 * 72];    // [m][k], k-stride 72
    __shared__ short Bs[128 * 72];   // [n][k]

    const int tid = threadIdx.x;
    const int lane = tid & 63;
    const int wv = tid >> 6;
    const int row0 = blockIdx.x * 32;

    const int ar = tid >> 3;         // 0..31
    const int ak = (tid & 7) * 8;    // 0..56
    const float* Ap = A + (size_t)(row0 + ar) * Mm + ak;

    const int bn = tid >> 1;         // 0..127
    const int bk = (tid & 1) * 32;
    const short* Bp = Bt + (size_t)bn * Mm + bk;

    const int fm = lane & 15;
    const int fk = (lane >> 4) * 8;

    float4v acc[2][2] = {};

    for (int k0 = 0; k0 < Mm; k0 += 64) {
        float4 a0 = *(const float4*)(Ap + k0);
        float4 a1 = *(const float4*)(Ap + k0 + 4);
        short8v b0 = *(const short8v*)(Bp + k0);
        short8v b1 = *(const short8v*)(Bp + k0 + 8);
        short8v b2 = *(const short8v*)(Bp + k0 + 16);
        short8v b3 = *(const short8v*)(Bp + k0 + 24);
        __syncthreads();
        short8v ap;
        ap[0] = f2bf(a0.x); ap[1] = f2bf(a0.y); ap[2] = f2bf(a0.z); ap[3] = f2bf(a0.w);
        ap[4] = f2bf(a1.x); ap[5] = f2bf(a1.y); ap[6] = f2bf(a1.z); ap[7] = f2bf(a1.w);
        *(short8v*)(&As[ar * 72 + ak]) = ap;
        *(short8v*)(&Bs[bn * 72 + bk +  0]) = b0;
        *(short8v*)(&Bs[bn * 72 + bk +  8]) = b1;
        *(short8v*)(&Bs[bn * 72 + bk + 16]) = b2;
        *(short8v*)(&Bs[bn * 72 + bk + 24]) = b3;
        __syncthreads();
#pragma unroll
        for (int ks = 0; ks < 2; ks++) {
            const int kk = ks * 32 + fk;
            short8v a0f = *(const short8v*)(&As[fm * 72 + kk]);
            short8v a1f = *(const short8v*)(&As[(16 + fm) * 72 + kk]);
            short8v b0f = *(const short8v*)(&Bs[(wv * 32 + fm) * 72 + kk]);
            short8v b1f = *(const short8v*)(&Bs[(wv * 32 + 16 + fm) * 72 + kk]);
            acc[0][0] = __builtin_amdgcn_mfma_f32_16x16x32_bf16(a0f, b0f, acc[0][0], 0, 0, 0);
            acc[0][1] = __builtin_amdgcn_mfma_f32_16x16x32_bf16(a0f, b1f, acc[0][1], 0, 0, 0);
            acc[1][0] = __builtin_amdgcn_mfma_f32_16x16x32_bf16(a1f, b0f, acc[1][0], 0, 0, 0);
            acc[1][1] = __builtin_amdgcn_mfma_f32_16x16x32_bf16(a1f, b1f, acc[1][1], 0, 0, 0);
        }
    }

    const int crow = (lane >> 4) * 4;
#pragma unroll
    for (int mt = 0; mt < 2; mt++)
#pragma unroll
        for (int nt = 0; nt < 2; nt++)
#pragma unroll
            for (int r = 0; r < 4; r++)
                C[(size_t)(row0 + mt * 16 + crow + r) * 128 + wv * 32 + nt * 16 + fm] =
                    acc[mt][nt][r];
}

// ---------------------------------------------------------------------------
// Fused tail: per 32-dst-row tile —
//   phase A: gather-aggregate graph conv for BOTH sources (curr_h, fused)
//            into LDS (one shared edge-list pass),
//   phase B: two f32 32x128 @ 128x128 GEMMs (A from LDS, W staged in 32-k
//            chunks), all f32,
//   phase C: epilogue in registers: (acc+b)*w per path, mean of 2, LayerNorm
//            (shuffle reduce over the 32-lane col group), ReLU, store.
// ---------------------------------------------------------------------------
__launch_bounds__(256, 2)
__global__ void k_tail(const float* __restrict__ curr_h, const float* __restrict__ fused,
                       const float* __restrict__ rs_o, const float* __restrict__ rs_i,
                       const int* __restrict__ row_start, const int* __restrict__ ebuf,
                       const float* __restrict__ Wc, const float* __restrict__ bc,
                       const float* __restrict__ conv_w,
                       const float* __restrict__ Wf, const float* __restrict__ bf,
                       const float* __restrict__ tdw,
                       const float* __restrict__ gamma, const float* __restrict__ beta,
                       float* __restrict__ out) {
    __shared__ float A1[32][132];   // conv-path agg    (pad 128->132)
    __shared__ float A2[32][132];   // top-down agg
    __shared__ float Bs[32][132];   // W chunk [k][n]

    const int tid = threadIdx.x;
    const int lane = tid & 63;
    const int wv = tid >> 6;
    const int row0 = blockIdx.x * 32;
    const int c = lane * 2;

    // ---- phase A: each wave aggregates 8 dst rows, both sources ----
    for (int rr = 0; rr < 8; rr++) {
        const int rl = wv * 8 + rr;
        const int d = row0 + rl;
        const int beg = row_start[d], end = row_start[d + 1];
        float a1x = 0.f, a1y = 0.f, a2x = 0.f, a2y = 0.f;
        int i = beg;
        for (; i + 1 < end; i += 2) {
            int s0 = ebuf[i], s1 = ebuf[i + 1];
            float r0v = rs_o[s0], r1v = rs_o[s1];
            float2 u0 = *(const float2*)(curr_h + (size_t)s0 * 128 + c);
            float2 v0 = *(const float2*)(fused  + (size_t)s0 * 128 + c);
            float2 u1 = *(const float2*)(curr_h + (size_t)s1 * 128 + c);
            float2 v1 = *(const float2*)(fused  + (size_t)s1 * 128 + c);
            a1x += u0.x * r0v + u1.x * r1v;
            a1y += u0.y * r0v + u1.y * r1v;
            a2x += v0.x * r0v + v1.x * r1v;
            a2y += v0.y * r0v + v1.y * r1v;
        }
        if (i < end) {
            int s0 = ebuf[i];
            float r0v = rs_o[s0];
            float2 u0 = *(const float2*)(curr_h + (size_t)s0 * 128 + c);
            float2 v0 = *(const float2*)(fused  + (size_t)s0 * 128 + c);
            a1x += u0.x * r0v; a1y += u0.y * r0v;
            a2x += v0.x * r0v; a2y += v0.y * r0v;
        }
        float ro = rs_o[d], ri = rs_i[d];
        float2 us = *(const float2*)(curr_h + (size_t)d * 128 + c);
        float2 vs = *(const float2*)(fused  + (size_t)d * 128 + c);
        *(float2*)(&A1[rl][c]) = float2{(a1x + us.x * ro) * ri, (a1y + us.y * ro) * ri};
        *(float2*)(&A2[rl][c]) = float2{(a2x + vs.x * ro) * ri, (a2y + vs.y * ro) * ri};
    }

    // ---- phase B: two 32x128 @ 128x128 f32 GEMMs from LDS ----
    const int tx = tid & 31, ty = tid >> 5;
    const int c4 = tx * 4, r0 = ty * 4;
    float acc[2][4][4] = {};

#pragma unroll
    for (int m = 0; m < 2; m++) {
        const float* W = m ? Wf : Wc;
        const float(*Asrc)[132] = m ? A2 : A1;
        for (int k0 = 0; k0 < 128; k0 += 32) {
            float4 bv[4];
#pragma unroll
            for (int t4 = 0; t4 < 4; t4++) {
                int idx = tid + t4 * 256;
                bv[t4] = *(const float4*)(W + (size_t)(k0 + (idx >> 5)) * 128 + (idx & 31) * 4);
            }
            __syncthreads();   // first iter: also guards phase-A LDS writes
#pragma unroll
            for (int t4 = 0; t4 < 4; t4++) {
                int idx = tid + t4 * 256;
                *(float4*)(&Bs[idx >> 5][(idx & 31) * 4]) = bv[t4];
            }
            __syncthreads();
#pragma unroll
            for (int kq = 0; kq < 8; kq++) {
                float4 a4[4];
#pragma unroll
                for (int i = 0; i < 4; i++)
                    a4[i] = *(const float4*)(&Asrc[r0 + i][k0 + kq * 4]);
#pragma unroll
                for (int q = 0; q < 4; q++) {
                    float4 b4 = *(const float4*)(&Bs[kq * 4 + q][c4]);
#pragma unroll
                    for (int i = 0; i < 4; i++) {
                        float av = ((const float*)&a4[i])[q];
                        acc[m][i][0] = fmaf(av, b4.x, acc[m][i][0]);
                        acc[m][i][1] = fmaf(av, b4.y, acc[m][i][1]);
                        acc[m][i][2] = fmaf(av, b4.z, acc[m][i][2]);
                        acc[m][i][3] = fmaf(av, b4.w, acc[m][i][3]);
                    }
                }
            }
        }
    }

    // ---- phase C: epilogue + LayerNorm + ReLU ----
    const float4 bcv = *(const float4*)(bc + c4);
    const float4 cwv = *(const float4*)(conv_w + c4);
    const float4 bfv = *(const float4*)(bf + c4);
    const float4 twv = *(const float4*)(tdw + c4);
    const float4 gv  = *(const float4*)(gamma + c4);
    const float4 bev = *(const float4*)(beta + c4);

    float res[4][4];
#pragma unroll
    for (int i = 0; i < 4; i++) {
#pragma unroll
        for (int j = 0; j < 4; j++) {
            float p1 = (acc[0][i][j] + ((const float*)&bcv)[j]) * ((const float*)&cwv)[j];
            float p2 = (acc[1][i][j] + ((const float*)&bfv)[j]) * ((const float*)&twv)[j];
            res[i][j] = (p1 + p2) * 0.5f;
        }
    }
#pragma unroll
    for (int i = 0; i < 4; i++) {
        float s1 = res[i][0] + res[i][1] + res[i][2] + res[i][3];
        float s2 = res[i][0] * res[i][0] + res[i][1] * res[i][1] +
                   res[i][2] * res[i][2] + res[i][3] * res[i][3];
        // reduce over the 32 lanes holding this row (same ty; xor masks < 32)
#pragma unroll
        for (int msk = 16; msk >= 1; msk >>= 1) {
            s1 += __shfl_xor(s1, msk);
            s2 += __shfl_xor(s2, msk);
        }
        float mu = s1 * (1.0f / 128.0f);
        float var = s2 * (1.0f / 128.0f) - mu * mu;
        float inv = rsqrtf(var + 1e-5f);
        float4 o;
        o.x = fmaxf((res[i][0] - mu) * inv * gv.x + bev.x, 0.0f);
        o.y = fmaxf((res[i][1] - mu) * inv * gv.y + bev.y, 0.0f);
        o.z = fmaxf((res[i][2] - mu) * inv * gv.z + bev.z, 0.0f);
        o.w = fmaxf((res[i][3] - mu) * inv * gv.w + bev.w, 0.0f);
        *(float4*)(out + (size_t)(row0 + r0 + i) * 128 + c4) = o;
    }
}

// ---------------------------------------------------------------------------
extern "C" void kernel_launch(void* const* d_in, const int* in_sizes, int n_in,
                              void* d_out, int out_size, void* d_ws, size_t ws_size,
                              hipStream_t stream) {
    const float* curr_h    = (const float*)d_in[0];
    const float* next_h    = (const float*)d_in[1];
    const float* curr_inc  = (const float*)d_in[2];
    const float* Wc        = (const float*)d_in[3];
    const float* bc        = (const float*)d_in[4];
    const float* Wf        = (const float*)d_in[5];
    const float* bf        = (const float*)d_in[6];
    const float* conv_w    = (const float*)d_in[7];
    const float* topDown_w = (const float*)d_in[8];
    const float* gamma     = (const float*)d_in[9];
    const float* beta      = (const float*)d_in[10];
    const int*   esrc      = (const int*)d_in[11];
    const int*   edst      = (const int*)d_in[12];
    float* out = (float*)d_out;

    // workspace layout (~12.6 MB; all offsets 16B-aligned)
    char* w = (char*)d_ws;
    int*   cnt_out = (int*)w;    w += (size_t)Nn * 4;        // zeroed in k_bt_zero
    int*   cnt_in  = (int*)w;    w += (size_t)Nn * 4;        // (contiguous with cnt_out)
    int*   cursor  = (int*)w;    w += (size_t)Nn * 4;
    int*   row_st  = (int*)w;    w += (size_t)16388 * 4;
    int*   ebuf    = (int*)w;    w += (size_t)Ee * 4;
    float* rs_out  = (float*)w;  w += (size_t)Nn * 4;
    float* rs_in   = (float*)w;  w += (size_t)Nn * 4;
    short* Bt      = (short*)w;  w += (size_t)Dd * Mm * 2;
    float* fused   = (float*)w;  w += (size_t)Nn * Dd * 4;

    // 1. B^T bf16 + zero counters (fused launch)
    k_bt_zero<<<1024 + 192, 256, 0, stream>>>(next_h, Bt, cnt_out);
    // 2. degree histogram
    k_deg_count<<<Ee / 256, 256, 0, stream>>>(esrc, edst, cnt_out, cnt_in);
    // 3. scan -> CSR row starts; rsqrt degrees
    k_scan<<<1, 1024, 0, stream>>>(cnt_in, cnt_out, row_st, rs_in, rs_out);
    // 4. CSR bucket fill
    k_fill<<<Ee / 256, 256, 0, stream>>>(esrc, edst, row_st, cursor, ebuf);
    // 5. fused = curr_inc @ next_h (bf16 MFMA, A streamed once from HBM)
    k_mfma_gemm<<<Nn / 32, 256, 0, stream>>>(curr_inc, Bt, fused);
    // 6. fused tail: dual graph-conv agg + dual GEMM + combine + LN + ReLU
    k_tail<<<Nn / 32, 256, 0, stream>>>(curr_h, fused, rs_out, rs_in, row_st, ebuf,
                                        Wc, bc, conv_w, Wf, bf, topDown_w,
                                        gamma, beta, out);
}